// Round 23
// baseline (31.091 us; speedup 1.0000x reference)
//
#include <hip/hip_runtime.h>
#include <stdint.h>

typedef __fp16    half2v __attribute__((ext_vector_type(2)));
typedef _Float16  f16x8  __attribute__((ext_vector_type(8)));
typedef float     f32x4  __attribute__((ext_vector_type(4)));
typedef uint32_t  u32x4  __attribute__((ext_vector_type(4)));

#define KSZ    5
#define NBATCH 16
#define NC     3
#define NH     256
#define NW     256
#define TW     16
#define TH     16
#define SWRD   12               // words per strip row (24 f16 cols)
#define SROWS  8                // strip rows per wave (4 + 2*2 halo)
#define SCPL   (SROWS * SWRD)   // 96 words per channel
#define SCOPY  (NC * SCPL)      // 288 words per copy
#define WREG   (2 * SCOPY)      // 576 words per wave region (dual copy)
#define PTS    20               // pbuf per-pixel stride in words (16B-aligned)
#define PPW    (64 * PTS)       // 1280 pbuf words per wave
#define NUNITW 144              // staging word-pair units per wave (3*8*6)

__device__ __forceinline__ uint32_t pack_f16x2(float lo, float hi) {
    half2v h = __builtin_amdgcn_cvt_pkrtz(lo, hi);
    return __builtin_bit_cast(uint32_t, h);
}

__device__ __forceinline__ float fdot2(uint32_t w, uint32_t v, float acc) {
#if __has_builtin(__builtin_amdgcn_fdot2)
    return __builtin_amdgcn_fdot2(__builtin_bit_cast(half2v, w),
                                  __builtin_bit_cast(half2v, v), acc, false);
#else
    half2v a = __builtin_bit_cast(half2v, w);
    half2v b = __builtin_bit_cast(half2v, v);
    return acc + (float)a.x * (float)b.x + (float)a.y * (float)b.y;
#endif
}

// SHARED slot->pair map (r7-VERIFIED): k-slot (s, dword d) holds tap-pair P,
// halves = taps (i, 2q), (i, 2q+1), P = i*3+q.
__device__ __forceinline__ int pair_of(int s, int d) {
    return (d < 2) ? (2 * s + d) : (8 + 2 * s + (d - 2));
}

// r7-VERIFIED prep: virtual filters vf = i*6+jj (jj<5 -> f=i*5+jj, else pad).
__global__ void prep_AB(const float* __restrict__ cw, const float* __restrict__ cb,
                        uint32_t* __restrict__ Atab, float* __restrict__ cbv)
{
    int idx = threadIdx.x + blockIdx.x * 256;
    if (idx < 1536) {
        int d  = idx & 3;
        int fl = (idx >> 2) & 15;
        int s  = (idx >> 6) & 3;
        int t3 = idx >> 8;            // 0..5
        int c  = t3 % 3, mt = t3 / 3;
        int vf = mt * 16 + fl;
        int P  = pair_of(s, d);
        float lo = 0.0f, hi = 0.0f;
        if (vf < 30 && (vf % 6) != 5 && P < 15) {
            int f = (vf / 6) * 5 + (vf % 6);
            int i = P / 3, q = P - 3 * i;
            const float* base = cw + f * 75 + c * 25 + i * 5;
            lo = base[2 * q];
            if (q < 2) hi = base[2 * q + 1];
        }
        Atab[idx] = pack_f16x2(lo, hi);
    } else if (idx < 1568) {
        int vf = idx - 1536;
        float v = 0.0f;
        if (vf < 30 && (vf % 6) != 5) v = cb[(vf / 6) * 5 + (vf % 6)];
        cbv[vf] = v;
    }
}

__global__ __launch_bounds__(256, 5)
void highorder23(const float* __restrict__ x,
                 const uint32_t* __restrict__ Atab,
                 const float* __restrict__ cbv,
                 float* __restrict__ out)
{
    // Per-WAVE private regions -> NO cross-wave dependency, NO barriers.
    __shared__ uint32_t lds_t[4 * WREG];     //  9216 B: 4 wave strips
    __shared__ uint32_t pbuf[4 * PPW];       // 20480 B: 4 wave pbuf slices

    const int tid = threadIdx.x;
    const int l   = tid & 63;
    const int wid = tid >> 6;
    const int fl  = l & 15;     // A row (vf) / B col (pixel col)
    const int s   = l >> 4;     // k-slice / D row group

    const int bx  = blockIdx.x & 15;
    const int by  = (blockIdx.x >> 4) & 15;
    const int b   = blockIdx.x >> 8;
    const int bw0 = bx * TW;
    const int bh0 = by * TH + wid * 4;   // this wave's 4-row band

    const float* xb = x + (size_t)b * NC * NH * NW;
    uint32_t* lw = lds_t + wid * WREG;
    uint32_t* pw = pbuf + wid * PPW;

    // A-fragments (weights) + bias (r7-verified)
    u32x4 afr[6];
    const u32x4* At4 = (const u32x4*)Atab;
    #pragma unroll
    for (int t3 = 0; t3 < 6; ++t3)
        afr[t3] = At4[(t3 * 4 + s) * 16 + fl];
    const f32x4* cbv4 = (const f32x4*)cbv;
    const f32x4 cbA = cbv4[s];       // rows vf = 4s+r
    const f32x4 cbB = cbv4[4 + s];   // rows vf = 16+4s+r

    // ---- Staging: THIS WAVE stages its own 8-row strip (r17-verified values;
    // rows bh0-2 .. bh0+5; word-pair unit u: c = u/48, r = (u%48)/6, j = u%6)
    #pragma unroll
    for (int it = 0; it < 3; ++it) {
        int u = l + it * 64;
        if (u < NUNITW) {
            int c   = u / 48;
            int rem = u - c * 48;
            int r   = rem / 6;
            int j   = rem - r * 6;
            int gh  = bh0 + r - 2;
            int g0  = bw0 + 4 * j - 2;
            bool rowok = (unsigned)gh < NH;
            const float* row = xb + c * NH * NW + gh * NW;
            float x0, x1, x2, x3, x4;
            if (rowok && g0 >= 0 && g0 + 4 < NW) {
                f32x4 v = *reinterpret_cast<const f32x4*>(row + g0);
                x0 = v[0]; x1 = v[1]; x2 = v[2]; x3 = v[3];
                x4 = row[g0 + 4];
            } else {
                x0 = (rowok && (unsigned)(g0)     < NW) ? row[g0]     : 0.0f;
                x1 = (rowok && (unsigned)(g0 + 1) < NW) ? row[g0 + 1] : 0.0f;
                x2 = (rowok && (unsigned)(g0 + 2) < NW) ? row[g0 + 2] : 0.0f;
                x3 = (rowok && (unsigned)(g0 + 3) < NW) ? row[g0 + 3] : 0.0f;
                x4 = (rowok && (unsigned)(g0 + 4) < NW) ? row[g0 + 4] : 0.0f;
            }
            const int idx0 = c * SCPL + r * SWRD + 2 * j;   // even -> 8B align
            uint2 wa; wa.x = pack_f16x2(x0, x1); wa.y = pack_f16x2(x2, x3);
            uint2 wb; wb.x = pack_f16x2(x1, x2); wb.y = pack_f16x2(x3, x4);
            *reinterpret_cast<uint2*>(&lw[idx0])         = wa;
            *reinterpret_cast<uint2*>(&lw[SCOPY + idx0]) = wb;
        }
    }
    // Wave-internal LDS visibility only (r14-proven pattern, rule 18)
    asm volatile("s_waitcnt lgkmcnt(0)" ::: "memory");
    __builtin_amdgcn_sched_barrier(0);

    // per-lane word offsets for pairs pair_of(s,d); P==15 -> clamp (its weight
    // pair wq3@s==3 is exactly zero, so the term is never consumed)
    int woff[4];
    #pragma unroll
    for (int d = 0; d < 4; ++d) {
        int P = pair_of(s, d);
        int i = P / 3, q = P - 3 * i;
        woff[d] = (P == 15) ? 0 : (i * SWRD + q);
    }
    const int abase = ((fl & 1) ? SCOPY : 0) + (fl >> 1);

    #pragma unroll
    for (int g = 0; g < 4; ++g) {
        // neighborhood of pixel row (bh0+g) = strip rows g..g+4
        const int bg = abase + g * SWRD;

        u32x4 bv[3];
        #pragma unroll
        for (int c = 0; c < 3; ++c)
            #pragma unroll
            for (int d = 0; d < 4; ++d)
                bv[c][d] = lw[bg + c * SCPL + woff[d]];

        // Phase 1 (r7-verified): wgt[vf][px] = conv + bias
        f32x4 a0 = cbA, a1 = cbB;
        #pragma unroll
        for (int c = 0; c < 3; ++c) {
            f16x8 B = __builtin_bit_cast(f16x8, bv[c]);
            a0 = __builtin_amdgcn_mfma_f32_16x16x32_f16(
                     __builtin_bit_cast(f16x8, afr[c]),     B, a0, 0, 0, 0);
            a1 = __builtin_amdgcn_mfma_f32_16x16x32_f16(
                     __builtin_bit_cast(f16x8, afr[3 + c]), B, a1, 0, 0, 0);
        }

        // In-lane pairs (r7-verified): rows 4s+r -> pairs 2s,2s+1,8+2s,9+2s
        uint32_t wq0 = pack_f16x2(a0[0], a0[1]);
        uint32_t wq1 = pack_f16x2(a0[2], a0[3]);
        uint32_t wq2 = pack_f16x2(a1[0], a1[1]);
        uint32_t wq3 = pack_f16x2(a1[2], a1[3]);

        // b64 writes into THIS WAVE's pbuf slice; t=15 slot never consumed.
        const int pb = (g * 16 + fl) * PTS;
        uint2 w01; w01.x = wq0; w01.y = wq1;
        uint2 w23; w23.x = wq2; w23.y = wq3;
        *reinterpret_cast<uint2*>(&pw[pb + 2 * s])     = w01;
        *reinterpret_cast<uint2*>(&pw[pb + 8 + 2 * s]) = w23;
    }

    // nb reads (lds strip stable; issue before the pbuf wait — r13 win)
    const int px  = l & 15;
    const int py2 = l >> 4;      // row within this wave's 4-row band
    const uint32_t* basep = lw + ((px & 1) ? SCOPY : 0) + (px >> 1);

    uint32_t nb[45];
    #pragma unroll
    for (int c = 0; c < NC; ++c)
        #pragma unroll
        for (int i = 0; i < KSZ; ++i)
            #pragma unroll
            for (int q = 0; q < 3; ++q)
                nb[c * 15 + i * 3 + q] =
                    basep[c * SCPL + (py2 + i) * SWRD + q];

    // pbuf producer->consumer is wave-internal: drain DS then read
    asm volatile("s_waitcnt lgkmcnt(0)" ::: "memory");
    __builtin_amdgcn_sched_barrier(0);

    // ---- Phase 2 (r13-verified): weight pairs via 4x ds_read_b128; split
    // fdot2 chains (depth 8) for ILP.
    u32x4 wp4[4];
    const int rb = (py2 * 16 + px) * PTS;
    #pragma unroll
    for (int r = 0; r < 4; ++r)
        wp4[r] = *reinterpret_cast<const u32x4*>(&pw[rb + 4 * r]);

    float* ob = out + (size_t)b * NC * NH * NW
                    + (size_t)(bh0 + py2) * NW + (bw0 + px);
    #pragma unroll
    for (int c = 0; c < NC; ++c) {
        // residual: center tap (i=2,j=2) = lo half of pair (i=2,q=1) -> idx 7
        half2v ctr = __builtin_bit_cast(half2v, nb[c * 15 + 7]);
        float sumA = (float)ctr.x;
        float sumB = 0.0f;
        #pragma unroll
        for (int t = 0; t < 8; ++t)
            sumA = fdot2(wp4[t >> 2][t & 3], nb[c * 15 + t], sumA);
        #pragma unroll
        for (int t = 8; t < 15; ++t)
            sumB = fdot2(wp4[t >> 2][t & 3], nb[c * 15 + t], sumB);
        ob[(size_t)c * NH * NW] = sumA + sumB;
    }
}

extern "C" void kernel_launch(void* const* d_in, const int* in_sizes, int n_in,
                              void* d_out, int out_size, void* d_ws, size_t ws_size,
                              hipStream_t stream)
{
    const float* x  = (const float*)d_in[0];
    const float* cw = (const float*)d_in[1];
    const float* cb = (const float*)d_in[2];
    float* out      = (float*)d_out;
    uint32_t* Atab  = (uint32_t*)d_ws;                    // 6144 B
    float*    cbv   = (float*)((char*)d_ws + 6144);       // 128 B

    prep_AB<<<7, 256, 0, stream>>>(cw, cb, Atab, cbv);

    dim3 grid(NBATCH * (NH / TH) * (NW / TW));   // 4096 blocks
    highorder23<<<grid, 256, 0, stream>>>(x, Atab, cbv, out);
}

// Round 24
// 27.679 us; speedup vs baseline: 1.1233x; 1.1233x over previous
//
#include <hip/hip_runtime.h>
#include <stdint.h>

typedef __fp16    half2v __attribute__((ext_vector_type(2)));
typedef _Float16  f16x8  __attribute__((ext_vector_type(8)));
typedef float     f32x4  __attribute__((ext_vector_type(4)));
typedef uint32_t  u32x4  __attribute__((ext_vector_type(4)));

#define KSZ    5
#define NBATCH 16
#define NC     3
#define NH     256
#define NW     256
#define TW     16
#define TH     16
#define TROWS  20
#define TWRD   12               // u32 words per tile row (24 f16 cols)
#define CPLANE (TROWS * TWRD)   // 240
#define COPYW  (NC * CPLANE)    // 720
#define PTS    20               // pbuf per-pixel stride in words (16B-aligned)
#define NUNIT  (COPYW / 2)      // 360 word-pair staging units

__device__ __forceinline__ uint32_t pack_f16x2(float lo, float hi) {
    half2v h = __builtin_amdgcn_cvt_pkrtz(lo, hi);
    return __builtin_bit_cast(uint32_t, h);
}

// SHARED slot->pair map (r7-VERIFIED): k-slot (s, dword d) holds tap-pair P,
// halves = taps (i, 2q), (i, 2q+1), P = i*3+q.
__device__ __forceinline__ int pair_of(int s, int d) {
    return (d < 2) ? (2 * s + d) : (8 + 2 * s + (d - 2));
}

// r7-VERIFIED prep: virtual filters vf = i*6+jj (jj<5 -> f=i*5+jj, else pad).
__global__ void prep_AB(const float* __restrict__ cw, const float* __restrict__ cb,
                        uint32_t* __restrict__ Atab, float* __restrict__ cbv)
{
    int idx = threadIdx.x + blockIdx.x * 256;
    if (idx < 1536) {
        int d  = idx & 3;
        int fl = (idx >> 2) & 15;
        int s  = (idx >> 6) & 3;
        int t3 = idx >> 8;            // 0..5
        int c  = t3 % 3, mt = t3 / 3;
        int vf = mt * 16 + fl;
        int P  = pair_of(s, d);
        float lo = 0.0f, hi = 0.0f;
        if (vf < 30 && (vf % 6) != 5 && P < 15) {
            int f = (vf / 6) * 5 + (vf % 6);
            int i = P / 3, q = P - 3 * i;
            const float* base = cw + f * 75 + c * 25 + i * 5;
            lo = base[2 * q];
            if (q < 2) hi = base[2 * q + 1];
        }
        Atab[idx] = pack_f16x2(lo, hi);
    } else if (idx < 1568) {
        int vf = idx - 1536;
        float v = 0.0f;
        if (vf < 30 && (vf % 6) != 5) v = cb[(vf / 6) * 5 + (vf % 6)];
        cbv[vf] = v;
    }
}

__global__ __launch_bounds__(256, 4)
void highorder24(const float* __restrict__ x,
                 const uint32_t* __restrict__ Atab,
                 const float* __restrict__ cbv,
                 float* __restrict__ out)
{
    __shared__ uint32_t lds_t[2 * COPYW];        // 5760 B dual-copy tile
    __shared__ uint32_t pbuf[TH * 16 * PTS];     // 20480 B [py][px][t(20)]

    const int tid = threadIdx.x;
    const int l   = tid & 63;
    const int w   = tid >> 6;
    const int fl  = l & 15;     // A row (vf) / B col (pixel col)
    const int s   = l >> 4;     // k-slice / D row group

    const int bx  = blockIdx.x & 15;
    const int by  = (blockIdx.x >> 4) & 15;
    const int b   = blockIdx.x >> 8;
    const int bw0 = bx * TW;
    const int bh0 = by * TH;

    const float* xb = x + (size_t)b * NC * NH * NW;

    // A-fragments (weights) + bias (r7-verified)
    u32x4 afr[6];
    const u32x4* At4 = (const u32x4*)Atab;
    #pragma unroll
    for (int t3 = 0; t3 < 6; ++t3)
        afr[t3] = At4[(t3 * 4 + s) * 16 + fl];
    const f32x4* cbv4 = (const f32x4*)cbv;
    const f32x4 cbA = cbv4[s];       // rows vf = 4s+r
    const f32x4 cbB = cbv4[4 + s];   // rows vf = 16+4s+r

    // ---- Staging, vectorized producer (r17-verified verbatim)
    #pragma unroll
    for (int it = 0; it < 2; ++it) {
        int u = tid + it * 256;
        if (u < NUNIT) {
            int c   = u / 120;            // CPLANE/2
            int rem = u - c * 120;
            int r   = rem / 6;
            int j   = rem - r * 6;
            int gh  = bh0 + r - 2;
            int g0  = bw0 + 4 * j - 2;
            bool rowok = (unsigned)gh < NH;
            const float* row = xb + c * NH * NW + gh * NW;
            float x0, x1, x2, x3, x4;
            if (rowok && g0 >= 0 && g0 + 4 < NW) {
                f32x4 v = *reinterpret_cast<const f32x4*>(row + g0);
                x0 = v[0]; x1 = v[1]; x2 = v[2]; x3 = v[3];
                x4 = row[g0 + 4];
            } else {
                x0 = (rowok && (unsigned)(g0)     < NW) ? row[g0]     : 0.0f;
                x1 = (rowok && (unsigned)(g0 + 1) < NW) ? row[g0 + 1] : 0.0f;
                x2 = (rowok && (unsigned)(g0 + 2) < NW) ? row[g0 + 2] : 0.0f;
                x3 = (rowok && (unsigned)(g0 + 3) < NW) ? row[g0 + 3] : 0.0f;
                x4 = (rowok && (unsigned)(g0 + 4) < NW) ? row[g0 + 4] : 0.0f;
            }
            const int idx0 = 2 * u;       // even -> 8B aligned
            uint2 wa; wa.x = pack_f16x2(x0, x1); wa.y = pack_f16x2(x2, x3);
            uint2 wb; wb.x = pack_f16x2(x1, x2); wb.y = pack_f16x2(x3, x4);
            *reinterpret_cast<uint2*>(&lds_t[idx0])         = wa;
            *reinterpret_cast<uint2*>(&lds_t[COPYW + idx0]) = wb;
        }
    }
    __syncthreads();

    // per-lane word offsets for pairs pair_of(s,d); P==15 -> clamp (its weight
    // pair wq3@s==3 is exactly zero, so the term is never consumed)
    int woff[4];
    #pragma unroll
    for (int d = 0; d < 4; ++d) {
        int P = pair_of(s, d);
        int i = P / 3, q = P - 3 * i;
        woff[d] = (P == 15) ? 0 : (i * TWRD + q);
    }
    const int abase = ((fl & 1) ? COPYW : 0) + (fl >> 1);

    #pragma unroll
    for (int g = 0; g < 4; ++g) {
        const int py = w * 4 + g;
        const int bg = abase + py * TWRD;

        u32x4 bv[3];
        #pragma unroll
        for (int c = 0; c < 3; ++c)
            #pragma unroll
            for (int d = 0; d < 4; ++d)
                bv[c][d] = lds_t[bg + c * CPLANE + woff[d]];

        // Phase 1 (r7-verified): wgt[vf][px] = conv + bias
        f32x4 a0 = cbA, a1 = cbB;
        #pragma unroll
        for (int c = 0; c < 3; ++c) {
            f16x8 B = __builtin_bit_cast(f16x8, bv[c]);
            a0 = __builtin_amdgcn_mfma_f32_16x16x32_f16(
                     __builtin_bit_cast(f16x8, afr[c]),     B, a0, 0, 0, 0);
            a1 = __builtin_amdgcn_mfma_f32_16x16x32_f16(
                     __builtin_bit_cast(f16x8, afr[3 + c]), B, a1, 0, 0, 0);
        }

        // In-lane pairs (r7-verified): rows 4s+r -> pairs 2s,2s+1,8+2s,9+2s
        uint32_t wq0 = pack_f16x2(a0[0], a0[1]);
        uint32_t wq1 = pack_f16x2(a0[2], a0[3]);
        uint32_t wq2 = pack_f16x2(a1[0], a1[1]);
        uint32_t wq3 = pack_f16x2(a1[2], a1[3]);

        // b64 writes; slot t=15 (s==3, wq3) is written but never consumed.
        const int pb = (py * 16 + fl) * PTS;
        uint2 w01; w01.x = wq0; w01.y = wq1;
        uint2 w23; w23.x = wq2; w23.y = wq3;
        *reinterpret_cast<uint2*>(&pbuf[pb + 2 * s])     = w01;
        *reinterpret_cast<uint2*>(&pbuf[pb + 8 + 2 * s]) = w23;
    }

    // nb reads HOISTED above the barrier (r13 win): lds_t stable since barrier 1
    const int px  = tid & 15;
    const int py2 = tid >> 4;
    const uint32_t* basep = lds_t + ((px & 1) ? COPYW : 0) + (px >> 1);

    uint32_t nb[45];
    #pragma unroll
    for (int c = 0; c < NC; ++c)
        #pragma unroll
        for (int i = 0; i < KSZ; ++i)
            #pragma unroll
            for (int q = 0; q < 3; ++q)
                nb[c * 15 + i * 3 + q] =
                    basep[c * CPLANE + (py2 + i) * TWRD + q];

    __syncthreads();

    // ---- Phase 2: packed-f16 FMA accumulation (v_pk_fma_f16, full-rate
    // VOP3P) replacing v_dot2_f32_f16 (r4 evidence: dot2 issues at ~2x cost).
    // Two f16x2 accumulators per channel (chain depth 8) + f32 combine.
    u32x4 wp4[4];
    const int rb = (py2 * 16 + px) * PTS;
    #pragma unroll
    for (int r = 0; r < 4; ++r)
        wp4[r] = *reinterpret_cast<const u32x4*>(&pbuf[rb + 4 * r]);

    float* ob = out + (size_t)b * NC * NH * NW
                    + (size_t)(bh0 + py2) * NW + (bw0 + px);
    #pragma unroll
    for (int c = 0; c < NC; ++c) {
        // residual: center tap (i=2,j=2) = lo half of pair idx 7 -> init accA.x
        uint32_t accA = nb[c * 15 + 7] & 0xFFFFu;   // (ctr, 0) as f16x2
        uint32_t accB = 0u;
        #pragma unroll
        for (int t = 0; t < 8; ++t)
            asm("v_pk_fma_f16 %0, %1, %2, %0"
                : "+v"(accA)
                : "v"(wp4[t >> 2][t & 3]), "v"(nb[c * 15 + t]));
        #pragma unroll
        for (int t = 8; t < 15; ++t)
            asm("v_pk_fma_f16 %0, %1, %2, %0"
                : "+v"(accB)
                : "v"(wp4[t >> 2][t & 3]), "v"(nb[c * 15 + t]));
        half2v hA = __builtin_bit_cast(half2v, accA);
        half2v hB = __builtin_bit_cast(half2v, accB);
        ob[(size_t)c * NH * NW] =
            ((float)hA.x + (float)hA.y) + ((float)hB.x + (float)hB.y);
    }
}

extern "C" void kernel_launch(void* const* d_in, const int* in_sizes, int n_in,
                              void* d_out, int out_size, void* d_ws, size_t ws_size,
                              hipStream_t stream)
{
    const float* x  = (const float*)d_in[0];
    const float* cw = (const float*)d_in[1];
    const float* cb = (const float*)d_in[2];
    float* out      = (float*)d_out;
    uint32_t* Atab  = (uint32_t*)d_ws;                    // 6144 B
    float*    cbv   = (float*)((char*)d_ws + 6144);       // 128 B

    prep_AB<<<7, 256, 0, stream>>>(cw, cb, Atab, cbv);

    dim3 grid(NBATCH * (NH / TH) * (NW / TW));   // 4096 blocks
    highorder24<<<grid, 256, 0, stream>>>(x, Atab, cbv, out);
}